// Round 1
// baseline (132.950 us; speedup 1.0000x reference)
//
#include <hip/hip_runtime.h>

typedef short bf16x8 __attribute__((ext_vector_type(8)));
typedef float f32x4 __attribute__((ext_vector_type(4)));
typedef unsigned short u16;
typedef unsigned int u32;

#define DEVI static __device__ __forceinline__

// Problem constants
#define NB 16
#define NS 2048
#define NW 768
#define NH 64

DEVI u16 f2bf(float x) {
  u32 u = __builtin_bit_cast(u32, x);
  u += 0x7fffu + ((u >> 16) & 1u);
  return (u16)(u >> 16);
}

DEVI f32x4 mfma16(bf16x8 a, bf16x8 b, f32x4 c) {
  return __builtin_amdgcn_mfma_f32_16x16x32_bf16(a, b, c, 0, 0, 0);
}

// XOR swizzle for width-64-bf16 LDS tiles: breaks the 128B-row-stride bank conflict.
DEVI int swz(int row, int col) { return ((row * 64 + col) * 2) ^ ((row & 7) << 4); }

// ---------------------------------------------------------------------------
// Kernel 0: rearrange Wq/Wk/Wv (fp32 [768][64]) into bf16 MFMA-B-fragment order.
// Tile (p, nct, kch): 16 cols x 32 k; within tile, lane*16B holds the 8 bf16 of
// that lane's B-fragment: k = kch*32 + (lane>>4)*8 + i, n = nct*16 + (lane&15).
// 3*4*24 = 288 tiles * 1KB.
// ---------------------------------------------------------------------------
__global__ __launch_bounds__(256) void prep_weights(
    const float* __restrict__ Wq, const float* __restrict__ Wk,
    const float* __restrict__ Wv, u16* __restrict__ wsW) {
  int tid = blockIdx.x * 256 + threadIdx.x;
  int tile = tid >> 6, lane = tid & 63;
  int p = tile / 96, rem = tile % 96;
  int nct = rem / 24, kch = rem % 24;
  const float* Wsrc = (p == 0) ? Wq : ((p == 1) ? Wk : Wv);
  int k0 = kch * 32 + (lane >> 4) * 8;
  int n = nct * 16 + (lane & 15);
  u16 h[8];
#pragma unroll
  for (int i = 0; i < 8; i++) h[i] = f2bf(Wsrc[(k0 + i) * NH + n]);
  uint4 v;
  v.x = (u32)h[0] | ((u32)h[1] << 16);
  v.y = (u32)h[2] | ((u32)h[3] << 16);
  v.z = (u32)h[4] | ((u32)h[5] << 16);
  v.w = (u32)h[6] | ((u32)h[7] << 16);
  ((uint4*)wsW)[tile * 64 + lane] = v;
}

// ---------------------------------------------------------------------------
// Kernel 1: fused QKV projection. BM=128 rows, BK=64, 4 waves.
// Wave w computes rows [w*32, w*32+32) x all 192 output cols (12 col-tiles).
// Writes Q,K as bf16 [b][s][64]; V transposed as bf16 [b][64][s].
// ---------------------------------------------------------------------------
__global__ __launch_bounds__(256) void qkv_proj(
    const float* __restrict__ inp, const u16* __restrict__ wsW,
    const float* __restrict__ bq, const float* __restrict__ bk,
    const float* __restrict__ bv, u16* __restrict__ Q, u16* __restrict__ K,
    u16* __restrict__ Vt) {
  __shared__ u16 A_lds[128 * 64];    // 16 KB, swizzled
  __shared__ u16 W_lds[24 * 512];    // 24 KB: 24 tiles of 1KB in frag order
  int tid = threadIdx.x;
  int w = tid >> 6, lane = tid & 63, g = lane >> 4, l15 = lane & 15;
  int row0 = blockIdx.x * 128;

  f32x4 acc[2][12];
#pragma unroll
  for (int rt = 0; rt < 2; rt++)
#pragma unroll
    for (int ct = 0; ct < 12; ct++) acc[rt][ct] = (f32x4)0.0f;

  for (int chunk = 0; chunk < 12; chunk++) {
    int k0 = chunk * 64;
    __syncthreads();  // protect previous iteration's reads
    // Stage A: input[row0..+128][k0..+64] fp32 -> bf16 swizzled LDS
#pragma unroll
    for (int p = 0; p < 8; p++) {
      int id = tid + p * 256;
      int r = id >> 4, c4 = (id & 15) * 4;
      const float4 v =
          *(const float4*)(inp + (size_t)(row0 + r) * NW + k0 + c4);
      ushort4 h4;
      h4.x = f2bf(v.x); h4.y = f2bf(v.y); h4.z = f2bf(v.z); h4.w = f2bf(v.w);
      *(ushort4*)((char*)A_lds + swz(r, c4)) = h4;
    }
    // Stage W: 24 tiles (12 col-tiles x 2 k-sub) of 1KB, already in frag order
#pragma unroll
    for (int p = 0; p < 6; p++) {
      int id = tid + p * 256;            // 0..1535 (16B units)
      int t = id >> 6, lsub = id & 63;   // t: local tile 0..23 = ct*2+kk
      int gt = (t >> 1) * 24 + chunk * 2 + (t & 1);
      ((uint4*)W_lds)[t * 64 + lsub] = ((const uint4*)wsW)[gt * 64 + lsub];
    }
    __syncthreads();
    // A fragments
    bf16x8 af[2][2];
#pragma unroll
    for (int rt = 0; rt < 2; rt++)
#pragma unroll
      for (int kk = 0; kk < 2; kk++) {
        int row = w * 32 + rt * 16 + l15;
        af[rt][kk] =
            *(const bf16x8*)((const char*)A_lds + swz(row, kk * 32 + g * 8));
      }
#pragma unroll
    for (int ct = 0; ct < 12; ct++)
#pragma unroll
      for (int kk = 0; kk < 2; kk++) {
        bf16x8 bf = *(const bf16x8*)((const char*)W_lds +
                                     ((ct * 2 + kk) * 1024 + lane * 16));
        acc[0][ct] = mfma16(af[0][kk], bf, acc[0][ct]);
        acc[1][ct] = mfma16(af[1][kk], bf, acc[1][ct]);
      }
  }

  // Epilogue: add bias, store bf16. Q/K row-major; V transposed [b][h][s].
  int b = row0 >> 11, s0b = row0 & 2047;
#pragma unroll
  for (int ct = 0; ct < 12; ct++) {
    int p3 = ct >> 2, n = (ct & 3) * 16 + l15;
    const float* bias = (p3 == 0) ? bq : ((p3 == 1) ? bk : bv);
    float bb = bias[n];
#pragma unroll
    for (int rt = 0; rt < 2; rt++) {
      int srow = s0b + w * 32 + rt * 16 + g * 4;
      if (p3 == 0) {
        u16* dst = Q + ((size_t)(b * NS + srow) * NH + n);
#pragma unroll
        for (int reg = 0; reg < 4; reg++)
          dst[(size_t)reg * NH] = f2bf(acc[rt][ct][reg] + bb);
      } else if (p3 == 1) {
        u16* dst = K + ((size_t)(b * NS + srow) * NH + n);
#pragma unroll
        for (int reg = 0; reg < 4; reg++)
          dst[(size_t)reg * NH] = f2bf(acc[rt][ct][reg] + bb);
      } else {
        ushort4 h4;
        h4.x = f2bf(acc[rt][ct][0] + bb);
        h4.y = f2bf(acc[rt][ct][1] + bb);
        h4.z = f2bf(acc[rt][ct][2] + bb);
        h4.w = f2bf(acc[rt][ct][3] + bb);
        *(ushort4*)(Vt + (size_t)b * NH * NS + (size_t)n * NS + srow) = h4;
      }
    }
  }
}

// ---------------------------------------------------------------------------
// Kernel 2: flash attention. Block: batch b, 128 q-rows, 4 waves x 32 rows.
// KV tiles of 64 keys; online softmax; key-padding mask as select-to-zero.
// ---------------------------------------------------------------------------
__global__ __launch_bounds__(256) void attn(
    const u16* __restrict__ Q, const u16* __restrict__ K,
    const u16* __restrict__ Vt, const int* __restrict__ mask,
    float* __restrict__ out) {
  __shared__ u16 K_lds[64 * 64];   // [key][h] swizzled
  __shared__ u16 V_lds[64 * 64];   // [h][key] swizzled
  __shared__ u16 P_lds[128 * 64];  // [q][key] swizzled
  int tid = threadIdx.x;
  int w = tid >> 6, lane = tid & 63, g = lane >> 4, l15 = lane & 15;
  int q0 = blockIdx.x * 128;
  int b = blockIdx.y;
  const u16* Qb = Q + (size_t)b * NS * NH;
  const u16* Kb = K + (size_t)b * NS * NH;
  const u16* Vb = Vt + (size_t)b * NH * NS;
  const int* mb = mask + b * NS;

  // Q fragments, hoisted (read straight from global; each row read once)
  bf16x8 qf[2][2];
#pragma unroll
  for (int rt = 0; rt < 2; rt++)
#pragma unroll
    for (int kk = 0; kk < 2; kk++)
      qf[rt][kk] = *(const bf16x8*)(Qb +
                                    (size_t)(q0 + w * 32 + rt * 16 + l15) * NH +
                                    kk * 32 + g * 8);

  f32x4 acc[2][4];
  float m_run[2][4], l_run[2][4];
#pragma unroll
  for (int rt = 0; rt < 2; rt++) {
#pragma unroll
    for (int ht = 0; ht < 4; ht++) acc[rt][ht] = (f32x4)0.0f;
#pragma unroll
    for (int reg = 0; reg < 4; reg++) {
      m_run[rt][reg] = -3.0e38f;
      l_run[rt][reg] = 0.0f;
    }
  }

  for (int t = 0; t < 32; t++) {
    int kv0 = t * 64;
    // Stage K tile [64 keys][64 h] and V^T tile [64 h][64 keys]
#pragma unroll
    for (int p = 0; p < 2; p++) {
      int id = tid + p * 256;
      int r = id >> 3, c8 = (id & 7) * 8;
      uint4 kv_ = *(const uint4*)(Kb + (size_t)(kv0 + r) * NH + c8);
      *(uint4*)((char*)K_lds + swz(r, c8)) = kv_;
      uint4 vv_ = *(const uint4*)(Vb + (size_t)r * NS + kv0 + c8);
      *(uint4*)((char*)V_lds + swz(r, c8)) = vv_;
    }
    int mv[4];
#pragma unroll
    for (int ct = 0; ct < 4; ct++) mv[ct] = mb[kv0 + ct * 16 + l15];
    __syncthreads();

    // S = Q K^T for this tile: per wave 32 q x 64 keys
    f32x4 sf[2][4];
#pragma unroll
    for (int rt = 0; rt < 2; rt++)
#pragma unroll
      for (int ct = 0; ct < 4; ct++) sf[rt][ct] = (f32x4)0.0f;
#pragma unroll
    for (int ct = 0; ct < 4; ct++)
#pragma unroll
      for (int kk = 0; kk < 2; kk++) {
        int rowk = ct * 16 + l15;
        bf16x8 kf =
            *(const bf16x8*)((const char*)K_lds + swz(rowk, kk * 32 + g * 8));
        sf[0][ct] = mfma16(qf[0][kk], kf, sf[0][ct]);
        sf[1][ct] = mfma16(qf[1][kk], kf, sf[1][ct]);
      }

    // Online softmax per row-tile
#pragma unroll
    for (int rt = 0; rt < 2; rt++) {
      float pr[4][4], tm[4];
#pragma unroll
      for (int reg = 0; reg < 4; reg++) tm[reg] = -3.0e38f;
#pragma unroll
      for (int ct = 0; ct < 4; ct++)
#pragma unroll
        for (int reg = 0; reg < 4; reg++) {
          float sv = sf[rt][ct][reg] * 0.125f;  // 1/sqrt(64)
          pr[ct][reg] = sv;
          if (mv[ct]) tm[reg] = fmaxf(tm[reg], sv);
        }
#pragma unroll
      for (int o = 1; o < 16; o <<= 1)
#pragma unroll
        for (int reg = 0; reg < 4; reg++)
          tm[reg] = fmaxf(tm[reg], __shfl_xor(tm[reg], o, 64));
      float corr[4], rs[4];
#pragma unroll
      for (int reg = 0; reg < 4; reg++) {
        float mn = fmaxf(m_run[rt][reg], tm[reg]);
        corr[reg] = __expf(m_run[rt][reg] - mn);
        m_run[rt][reg] = mn;
        rs[reg] = 0.0f;
      }
#pragma unroll
      for (int ct = 0; ct < 4; ct++)
#pragma unroll
        for (int reg = 0; reg < 4; reg++) {
          float p = mv[ct] ? __expf(pr[ct][reg] - m_run[rt][reg]) : 0.0f;
          pr[ct][reg] = p;
          rs[reg] += p;
        }
#pragma unroll
      for (int o = 1; o < 16; o <<= 1)
#pragma unroll
        for (int reg = 0; reg < 4; reg++) rs[reg] += __shfl_xor(rs[reg], o, 64);
#pragma unroll
      for (int reg = 0; reg < 4; reg++)
        l_run[rt][reg] = l_run[rt][reg] * corr[reg] + rs[reg];
#pragma unroll
      for (int ht = 0; ht < 4; ht++)
#pragma unroll
        for (int reg = 0; reg < 4; reg++) acc[rt][ht][reg] *= corr[reg];
      // write P (bf16) to LDS for re-fragmentation
#pragma unroll
      for (int ct = 0; ct < 4; ct++)
#pragma unroll
        for (int reg = 0; reg < 4; reg++) {
          int q = w * 32 + rt * 16 + g * 4 + reg;
          int c = ct * 16 + l15;
          *(u16*)((char*)P_lds + swz(q, c)) = f2bf(pr[ct][reg]);
        }
    }
    __syncthreads();

    // O += P V
#pragma unroll
    for (int ks = 0; ks < 2; ks++) {
      bf16x8 pf[2];
#pragma unroll
      for (int rt = 0; rt < 2; rt++) {
        int rowq = w * 32 + rt * 16 + l15;
        pf[rt] =
            *(const bf16x8*)((const char*)P_lds + swz(rowq, ks * 32 + g * 8));
      }
#pragma unroll
      for (int ht = 0; ht < 4; ht++) {
        int rowh = ht * 16 + l15;
        bf16x8 vf =
            *(const bf16x8*)((const char*)V_lds + swz(rowh, ks * 32 + g * 8));
        acc[0][ht] = mfma16(pf[0], vf, acc[0][ht]);
        acc[1][ht] = mfma16(pf[1], vf, acc[1][ht]);
      }
    }
    __syncthreads();
  }

  // Epilogue: out[b][q][h] = acc / l  (fp32)
#pragma unroll
  for (int rt = 0; rt < 2; rt++)
#pragma unroll
    for (int ht = 0; ht < 4; ht++)
#pragma unroll
      for (int reg = 0; reg < 4; reg++) {
        int row = q0 + w * 32 + rt * 16 + g * 4 + reg;
        out[((size_t)b * NS + row) * NH + ht * 16 + l15] =
            acc[rt][ht][reg] / l_run[rt][reg];
      }
}

extern "C" void kernel_launch(void* const* d_in, const int* in_sizes, int n_in,
                              void* d_out, int out_size, void* d_ws,
                              size_t ws_size, hipStream_t stream) {
  const float* inp = (const float*)d_in[0];
  const int* mask = (const int*)d_in[1];
  const float* Wq = (const float*)d_in[2];
  const float* bq = (const float*)d_in[3];
  const float* Wk = (const float*)d_in[4];
  const float* bk = (const float*)d_in[5];
  const float* Wv = (const float*)d_in[6];
  const float* bv = (const float*)d_in[7];
  float* out = (float*)d_out;

  char* ws = (char*)d_ws;
  u16* wsW = (u16*)ws;                          // 288 KB (frag-ordered weights)
  u16* wsQ = (u16*)(ws + (1u << 20));           // 4 MB
  u16* wsK = (u16*)(ws + (1u << 20) + (4u << 20));
  u16* wsVt = (u16*)(ws + (1u << 20) + (8u << 20));

  prep_weights<<<dim3(72), dim3(256), 0, stream>>>(Wq, Wk, Wv, wsW);
  qkv_proj<<<dim3((NB * NS) / 128), dim3(256), 0, stream>>>(
      inp, wsW, bq, bk, bv, wsQ, wsK, wsVt);
  attn<<<dim3(NS / 128, NB), dim3(256), 0, stream>>>(wsQ, wsK, wsVt, mask, out);
}